// Round 14
// baseline (193.453 us; speedup 1.0000x reference)
//
#include <hip/hip_runtime.h>

#define HID 64
#define IN_DIM 128
#define RANGE_BITS 14
#define RANGE (1 << RANGE_BITS)   // 16384 nodes per bucket (64 KB LDS)
#define NB 7                      // ceil(100000 / 16384)
#define MCH 36                    // edge chunks
#define SCAN_TPB 512

// ---------------- dense: 2-way channel split, j-depth 32 ----------------
// Block = 128 nodes x 2 channel-halves. Thread (nid, half) computes channels
// [32*half, 32*half+32) for node nid: 32 independent FMA chains, 128 FMAs per
// x float4 load. z[node] = relu(x@W_in + b_in) . w_eff,  w_eff = W_g @ W_out.
__global__ __launch_bounds__(256) void k_dense(const float* __restrict__ x,
                                               const float* __restrict__ W_in,
                                               const float* __restrict__ b_in,
                                               const float* __restrict__ W_g,
                                               const float* __restrict__ W_out,
                                               float* __restrict__ z, int N) {
    __shared__ float weff_l[HID];
    __shared__ float part[128];
    if (threadIdx.x < HID) {
        float s = 0.0f;
#pragma unroll
        for (int jp = 0; jp < HID; ++jp)
            s = fmaf(W_g[threadIdx.x * HID + jp], W_out[jp], s);
        weff_l[threadIdx.x] = s;
    }
    __syncthreads();

    const int nid  = threadIdx.x & 127;   // node within block
    const int half = threadIdx.x >> 7;    // channel half (wave-uniform)
    int node = blockIdx.x * 128 + nid;
    if (node >= N) node = N - 1;          // clamped threads duplicate-write identical values

    float acc[32];
#pragma unroll
    for (int jj = 0; jj < 32; ++jj)
        acc[jj] = b_in[half * 32 + jj];   // wave-uniform -> s_load

    const float4* xrow = (const float4*)(x + (size_t)node * IN_DIM);
    for (int k4 = 0; k4 < IN_DIM / 4; ++k4) {
        float4 xv = xrow[k4];             // read once; 2nd half hits L1
        const float xk[4] = {xv.x, xv.y, xv.z, xv.w};
#pragma unroll
        for (int kk = 0; kk < 4; ++kk) {
            const float* wr = W_in + (k4 * 4 + kk) * HID + half * 32;  // wave-uniform
#pragma unroll
            for (int jj = 0; jj < 32; ++jj)
                acc[jj] = fmaf(xk[kk], wr[jj], acc[jj]);
        }
    }

    float zv = 0.0f;
#pragma unroll
    for (int jj = 0; jj < 32; ++jj)
        zv = fmaf(fmaxf(acc[jj], 0.0f), weff_l[half * 32 + jj], zv);

    if (half == 0) part[nid] = zv;
    __syncthreads();
    if (half == 1) z[node] = zv + part[nid];
}

// ---------------- pass A: binned degree count (LDS atomics only) ----------------
__global__ __launch_bounds__(SCAN_TPB) void k_binA(const int* __restrict__ dst,
                                                   int* __restrict__ part,
                                                   int E, int chunk) {
    __shared__ int cnt[RANGE];
    for (int i = threadIdx.x; i < RANGE; i += SCAN_TPB) cnt[i] = 0;
    __syncthreads();

    const int r = blockIdx.x % NB;
    const int lo = r << RANGE_BITS;
    const int e0 = (blockIdx.x / NB) * chunk;
    const int e1 = min(E, e0 + chunk);
    for (int e = e0 + (int)threadIdx.x * 4; e + 3 < e1; e += SCAN_TPB * 4) {
        int4 d4 = *(const int4*)(dst + e);
        unsigned v;
        v = (unsigned)(d4.x - lo); if (v < RANGE) atomicAdd(&cnt[v], 1);
        v = (unsigned)(d4.y - lo); if (v < RANGE) atomicAdd(&cnt[v], 1);
        v = (unsigned)(d4.z - lo); if (v < RANGE) atomicAdd(&cnt[v], 1);
        v = (unsigned)(d4.w - lo); if (v < RANGE) atomicAdd(&cnt[v], 1);
    }
    __syncthreads();

    int* outp = part + (size_t)blockIdx.x * RANGE;
    for (int i = threadIdx.x; i < RANGE; i += SCAN_TPB) outp[i] = cnt[i];
}

// ---------------- reduce deg -> dinv, zs = z * dinv ----------------
__global__ __launch_bounds__(256) void k_redDeg(const int* __restrict__ part,
                                                const float* __restrict__ z,
                                                float* __restrict__ dinv,
                                                float* __restrict__ zs, int N) {
    int i = blockIdx.x * blockDim.x + threadIdx.x;
    if (i >= N) return;
    const int r = i >> RANGE_BITS, idx = i & (RANGE - 1);
    int d = 0;
#pragma unroll 4
    for (int m = 0; m < MCH; ++m)
        d += part[((size_t)m * NB + r) * RANGE + idx];
    float di = rsqrtf((float)d + 1.0f);
    dinv[i] = di;
    zs[i]   = z[i] * di;
}

// ---------------- pass C: binned value scatter (LDS float atomics only) ----------------
__global__ __launch_bounds__(SCAN_TPB) void k_binC(const int* __restrict__ eidx,
                                                   const float* __restrict__ zs,
                                                   float* __restrict__ partf,
                                                   int E, int chunk) {
    __shared__ float acc[RANGE];
    for (int i = threadIdx.x; i < RANGE; i += SCAN_TPB) acc[i] = 0.0f;
    __syncthreads();

    const int r = blockIdx.x % NB;
    const int lo = r << RANGE_BITS;
    const int e0 = (blockIdx.x / NB) * chunk;
    const int e1 = min(E, e0 + chunk);
    for (int e = e0 + (int)threadIdx.x * 4; e + 3 < e1; e += SCAN_TPB * 4) {
        int4 s4 = *(const int4*)(eidx + e);        // src
        int4 d4 = *(const int4*)(eidx + E + e);    // dst
        unsigned v;
        v = (unsigned)(d4.x - lo); if (v < RANGE) atomicAdd(&acc[v], zs[s4.x]);
        v = (unsigned)(d4.y - lo); if (v < RANGE) atomicAdd(&acc[v], zs[s4.y]);
        v = (unsigned)(d4.z - lo); if (v < RANGE) atomicAdd(&acc[v], zs[s4.z]);
        v = (unsigned)(d4.w - lo); if (v < RANGE) atomicAdd(&acc[v], zs[s4.w]);
    }
    __syncthreads();

    float* outp = partf + (size_t)blockIdx.x * RANGE;
    for (int i = threadIdx.x; i < RANGE; i += SCAN_TPB) outp[i] = acc[i];
}

// ------- final: out = dinv * (sum partials + zs[self]) + (b_g.W_out + b_out) -------
__global__ __launch_bounds__(256) void k_redFinal(const float* __restrict__ partf,
                                                  const float* __restrict__ dinv,
                                                  const float* __restrict__ zs,
                                                  const float* __restrict__ b_g,
                                                  const float* __restrict__ W_out,
                                                  const float* __restrict__ b_out,
                                                  float* __restrict__ out, int N) {
    const int lane = threadIdx.x & 63;
    float c = b_g[lane] * W_out[lane];
#pragma unroll
    for (int off = 32; off > 0; off >>= 1)
        c += __shfl_xor(c, off, 64);
    c += b_out[0];

    int i = blockIdx.x * blockDim.x + threadIdx.x;
    if (i >= N) return;
    const int r = i >> RANGE_BITS, idx = i & (RANGE - 1);
    float a = zs[i];   // self-loop
#pragma unroll 4
    for (int m = 0; m < MCH; ++m)
        a += partf[((size_t)m * NB + r) * RANGE + idx];
    out[i] = fmaf(dinv[i], a, c);
}

// ---------------- launch ----------------

extern "C" void kernel_launch(void* const* d_in, const int* in_sizes, int n_in,
                              void* d_out, int out_size, void* d_ws, size_t ws_size,
                              hipStream_t stream) {
    const float* x     = (const float*)d_in[0];
    const int*   eidx  = (const int*)d_in[1];
    const float* W_in  = (const float*)d_in[2];
    const float* b_in  = (const float*)d_in[3];
    const float* W_g   = (const float*)d_in[4];
    const float* b_g   = (const float*)d_in[5];
    const float* W_out = (const float*)d_in[6];
    const float* b_out = (const float*)d_in[7];
    float* out = (float*)d_out;

    const int N = in_sizes[0] / IN_DIM;   // 100000
    const int E = in_sizes[1] / 2;        // 1600000

    // chunk: multiple of 4 covering E with MCH chunks
    const int chunk = (((E + MCH - 1) / MCH) + 3) & ~3;

    // ws layout: part[NB*MCH*RANGE] (int/float, reused) | z[N] | dinv[N] | zs[N]
    const size_t partElems = (size_t)NB * MCH * RANGE;
    int*   part  = (int*)d_ws;
    float* partf = (float*)d_ws;          // reused after k_redDeg consumed counts
    float* z     = (float*)d_ws + partElems;
    float* dinv  = z + N;
    float* zs    = dinv + N;

    k_binA<<<NB * MCH, SCAN_TPB, 0, stream>>>(eidx + E, part, E, chunk);
    k_dense<<<(N + 127) / 128, 256, 0, stream>>>(x, W_in, b_in, W_g, W_out, z, N);
    k_redDeg<<<(N + 255) / 256, 256, 0, stream>>>(part, z, dinv, zs, N);
    k_binC<<<NB * MCH, SCAN_TPB, 0, stream>>>(eidx, zs, partf, E, chunk);
    k_redFinal<<<(N + 255) / 256, 256, 0, stream>>>(partf, dinv, zs, b_g, W_out, b_out, out, N);
}

// Round 15
// 106.215 us; speedup vs baseline: 1.8213x; 1.8213x over previous
//
#include <hip/hip_runtime.h>

#define HID 64
#define IN_DIM 128
#define RANGE_BITS 14
#define RANGE (1 << RANGE_BITS)   // 16384 nodes per bucket (64 KB LDS)
#define NB 7                      // ceil(100000 / 16384)
#define MCH 36                    // edge chunks
#define SCAN_TPB 512

// ---------------- dense: j-split by BLOCK (keeps W on the scalar path) ----------------
// Block b: node group b>>1 (256 nodes, thread-per-node), channel half b&1.
// Each thread: acc[32] over one k-pass, x float4 stream with +1 prefetch.
// zpart[half][node] = relu-partial . w_eff_half; summed in k_redDeg.
__global__ __launch_bounds__(256) void k_dense(const float* __restrict__ x,
                                               const float* __restrict__ W_in,
                                               const float* __restrict__ b_in,
                                               const float* __restrict__ W_g,
                                               const float* __restrict__ W_out,
                                               float* __restrict__ zpart,
                                               int N, int Npad) {
    const int g = blockIdx.x >> 1;
    const int h = blockIdx.x & 1;          // SGPR -> W addressing provably uniform

    __shared__ float weff_l[32];
    if (threadIdx.x < 32) {
        const int j = h * 32 + threadIdx.x;
        float s = 0.0f;
#pragma unroll
        for (int jp = 0; jp < HID; ++jp)
            s = fmaf(W_g[j * HID + jp], W_out[jp], s);
        weff_l[threadIdx.x] = s;
    }
    __syncthreads();

    int node = g * 256 + threadIdx.x;
    if (node >= N) node = N - 1;           // clamped threads duplicate-write identical values

    float acc[32];
#pragma unroll
    for (int jj = 0; jj < 32; ++jj)
        acc[jj] = b_in[h * 32 + jj];       // uniform -> s_load

    const float4* xrow = (const float4*)(x + (size_t)node * IN_DIM);
    float4 xv = xrow[0];
    for (int k4 = 0; k4 < IN_DIM / 4 - 1; ++k4) {
        float4 xn = xrow[k4 + 1];          // prefetch next 16B while FMAs run
        const float xk[4] = {xv.x, xv.y, xv.z, xv.w};
#pragma unroll
        for (int kk = 0; kk < 4; ++kk) {
            const float* wr = W_in + (k4 * 4 + kk) * HID + h * 32;  // uniform -> s_load
#pragma unroll
            for (int jj = 0; jj < 32; ++jj)
                acc[jj] = fmaf(xk[kk], wr[jj], acc[jj]);
        }
        xv = xn;
    }
    {   // epilogue k4 = 31
        const int k4 = IN_DIM / 4 - 1;
        const float xk[4] = {xv.x, xv.y, xv.z, xv.w};
#pragma unroll
        for (int kk = 0; kk < 4; ++kk) {
            const float* wr = W_in + (k4 * 4 + kk) * HID + h * 32;
#pragma unroll
            for (int jj = 0; jj < 32; ++jj)
                acc[jj] = fmaf(xk[kk], wr[jj], acc[jj]);
        }
    }

    float zv = 0.0f;
#pragma unroll
    for (int jj = 0; jj < 32; ++jj)
        zv = fmaf(fmaxf(acc[jj], 0.0f), weff_l[jj], zv);
    zpart[(size_t)h * Npad + node] = zv;
}

// ---------------- pass A: binned degree count (LDS atomics only) ----------------
__global__ __launch_bounds__(SCAN_TPB) void k_binA(const int* __restrict__ dst,
                                                   int* __restrict__ part,
                                                   int E, int chunk) {
    __shared__ int cnt[RANGE];
    for (int i = threadIdx.x; i < RANGE; i += SCAN_TPB) cnt[i] = 0;
    __syncthreads();

    const int r = blockIdx.x % NB;
    const int lo = r << RANGE_BITS;
    const int e0 = (blockIdx.x / NB) * chunk;
    const int e1 = min(E, e0 + chunk);
    for (int e = e0 + (int)threadIdx.x * 4; e + 3 < e1; e += SCAN_TPB * 4) {
        int4 d4 = *(const int4*)(dst + e);
        unsigned v;
        v = (unsigned)(d4.x - lo); if (v < RANGE) atomicAdd(&cnt[v], 1);
        v = (unsigned)(d4.y - lo); if (v < RANGE) atomicAdd(&cnt[v], 1);
        v = (unsigned)(d4.z - lo); if (v < RANGE) atomicAdd(&cnt[v], 1);
        v = (unsigned)(d4.w - lo); if (v < RANGE) atomicAdd(&cnt[v], 1);
    }
    __syncthreads();

    int* outp = part + (size_t)blockIdx.x * RANGE;
    for (int i = threadIdx.x; i < RANGE; i += SCAN_TPB) outp[i] = cnt[i];
}

// ---------------- reduce deg -> dinv, z = zpart0+zpart1, zs = z * dinv ----------------
__global__ __launch_bounds__(256) void k_redDeg(const int* __restrict__ part,
                                                const float* __restrict__ zpart,
                                                float* __restrict__ dinv,
                                                float* __restrict__ zs,
                                                int N, int Npad) {
    int i = blockIdx.x * blockDim.x + threadIdx.x;
    if (i >= N) return;
    const int r = i >> RANGE_BITS, idx = i & (RANGE - 1);
    int d = 0;
#pragma unroll 4
    for (int m = 0; m < MCH; ++m)
        d += part[((size_t)m * NB + r) * RANGE + idx];
    float di = rsqrtf((float)d + 1.0f);
    dinv[i] = di;
    zs[i]   = (zpart[i] + zpart[(size_t)Npad + i]) * di;
}

// ---------------- pass C: binned value scatter (LDS float atomics only) ----------------
__global__ __launch_bounds__(SCAN_TPB) void k_binC(const int* __restrict__ eidx,
                                                   const float* __restrict__ zs,
                                                   float* __restrict__ partf,
                                                   int E, int chunk) {
    __shared__ float acc[RANGE];
    for (int i = threadIdx.x; i < RANGE; i += SCAN_TPB) acc[i] = 0.0f;
    __syncthreads();

    const int r = blockIdx.x % NB;
    const int lo = r << RANGE_BITS;
    const int e0 = (blockIdx.x / NB) * chunk;
    const int e1 = min(E, e0 + chunk);
    for (int e = e0 + (int)threadIdx.x * 4; e + 3 < e1; e += SCAN_TPB * 4) {
        int4 s4 = *(const int4*)(eidx + e);        // src
        int4 d4 = *(const int4*)(eidx + E + e);    // dst
        unsigned v;
        v = (unsigned)(d4.x - lo); if (v < RANGE) atomicAdd(&acc[v], zs[s4.x]);
        v = (unsigned)(d4.y - lo); if (v < RANGE) atomicAdd(&acc[v], zs[s4.y]);
        v = (unsigned)(d4.z - lo); if (v < RANGE) atomicAdd(&acc[v], zs[s4.z]);
        v = (unsigned)(d4.w - lo); if (v < RANGE) atomicAdd(&acc[v], zs[s4.w]);
    }
    __syncthreads();

    float* outp = partf + (size_t)blockIdx.x * RANGE;
    for (int i = threadIdx.x; i < RANGE; i += SCAN_TPB) outp[i] = acc[i];
}

// ------- final: out = dinv * (sum partials + zs[self]) + (b_g.W_out + b_out) -------
__global__ __launch_bounds__(256) void k_redFinal(const float* __restrict__ partf,
                                                  const float* __restrict__ dinv,
                                                  const float* __restrict__ zs,
                                                  const float* __restrict__ b_g,
                                                  const float* __restrict__ W_out,
                                                  const float* __restrict__ b_out,
                                                  float* __restrict__ out, int N) {
    const int lane = threadIdx.x & 63;
    float c = b_g[lane] * W_out[lane];
#pragma unroll
    for (int off = 32; off > 0; off >>= 1)
        c += __shfl_xor(c, off, 64);
    c += b_out[0];

    int i = blockIdx.x * blockDim.x + threadIdx.x;
    if (i >= N) return;
    const int r = i >> RANGE_BITS, idx = i & (RANGE - 1);
    float a = zs[i];   // self-loop
#pragma unroll 4
    for (int m = 0; m < MCH; ++m)
        a += partf[((size_t)m * NB + r) * RANGE + idx];
    out[i] = fmaf(dinv[i], a, c);
}

// ---------------- launch ----------------

extern "C" void kernel_launch(void* const* d_in, const int* in_sizes, int n_in,
                              void* d_out, int out_size, void* d_ws, size_t ws_size,
                              hipStream_t stream) {
    const float* x     = (const float*)d_in[0];
    const int*   eidx  = (const int*)d_in[1];
    const float* W_in  = (const float*)d_in[2];
    const float* b_in  = (const float*)d_in[3];
    const float* W_g   = (const float*)d_in[4];
    const float* b_g   = (const float*)d_in[5];
    const float* W_out = (const float*)d_in[6];
    const float* b_out = (const float*)d_in[7];
    float* out = (float*)d_out;

    const int N = in_sizes[0] / IN_DIM;   // 100000
    const int E = in_sizes[1] / 2;        // 1600000

    // chunk: multiple of 4 covering E with MCH chunks
    const int chunk = (((E + MCH - 1) / MCH) + 3) & ~3;

    // ws layout: part[NB*MCH*RANGE] (int/float, reused) | zpart[2*Npad] | dinv[N] | zs[N]
    const size_t partElems = (size_t)NB * MCH * RANGE;
    const int Npad = (N + 63) & ~63;
    int*   part  = (int*)d_ws;
    float* partf = (float*)d_ws;          // reused after k_redDeg consumed counts
    float* zpart = (float*)d_ws + partElems;
    float* dinv  = zpart + 2 * (size_t)Npad;
    float* zs    = dinv + N;

    const int nG = (N + 255) / 256;       // node groups
    k_binA<<<NB * MCH, SCAN_TPB, 0, stream>>>(eidx + E, part, E, chunk);
    k_dense<<<nG * 2, 256, 0, stream>>>(x, W_in, b_in, W_g, W_out, zpart, N, Npad);
    k_redDeg<<<(N + 255) / 256, 256, 0, stream>>>(part, zpart, dinv, zs, N, Npad);
    k_binC<<<NB * MCH, SCAN_TPB, 0, stream>>>(eidx, zs, partf, E, chunk);
    k_redFinal<<<(N + 255) / 256, 256, 0, stream>>>(partf, dinv, zs, b_g, W_out, b_out, out, N);
}

// Round 16
// 96.995 us; speedup vs baseline: 1.9945x; 1.0951x over previous
//
#include <hip/hip_runtime.h>

#define HID 64
#define IN_DIM 128
#define RANGE_BITS 14
#define RANGE (1 << RANGE_BITS)   // 16384 nodes per bucket (64 KB LDS)
#define NB 7                      // ceil(100000 / 16384)
#define MCH 36                    // edge chunks
#define SCAN_TPB 512
#define STAGE_K 16                // floats of each row staged per chunk
#define NCHUNK (IN_DIM / STAGE_K) // 8
#define LDSP 257                  // padded node-stride in transposed LDS tile

// ---------------- dense: block h-split + LDS-staged transposed x ----------------
// Block b: node group b>>1 (256 nodes), channel half h=b&1 (SGPR -> W scalar path).
// x staged in 8 chunks of [256 nodes][16 floats], transposed in LDS; each x byte
// fetched once per pass. acc[32]/thread.
__global__ __launch_bounds__(256) void k_dense(const float* __restrict__ x,
                                               const float* __restrict__ W_in,
                                               const float* __restrict__ b_in,
                                               const float* __restrict__ W_g,
                                               const float* __restrict__ W_out,
                                               float* __restrict__ zpart,
                                               int N, int Npad) {
    const int g = blockIdx.x >> 1;
    const int h = blockIdx.x & 1;          // SGPR -> W addressing provably uniform

    __shared__ float weff_l[32];
    __shared__ float ldsT[2][STAGE_K][LDSP];

    if (threadIdx.x < 32) {
        const int j = h * 32 + threadIdx.x;
        float s = 0.0f;
#pragma unroll
        for (int jp = 0; jp < HID; ++jp)
            s = fmaf(W_g[j * HID + jp], W_out[jp], s);
        weff_l[threadIdx.x] = s;
    }

    const int t = threadIdx.x;
    const int row0 = g * 256;
    int node = row0 + t;
    if (node >= N) node = N - 1;           // clamped threads duplicate-write identical values

    float acc[32];
#pragma unroll
    for (int jj = 0; jj < 32; ++jj)
        acc[jj] = b_in[h * 32 + jj];       // uniform -> s_load

    // staging registers: 4 float4 per thread per chunk (64 B)
    float4 rg[4];
    const int srow[4] = { (0 * 256 + t) >> 2, (1 * 256 + t) >> 2,
                          (2 * 256 + t) >> 2, (3 * 256 + t) >> 2 };
    const int scp = t & 3;

    // LOADC(c): coalesced 64-B-segment loads of chunk c into rg
#define LOADC(c)                                                                \
    {                                                                           \
        _Pragma("unroll")                                                       \
        for (int rr = 0; rr < 4; ++rr) {                                        \
            int grow = row0 + srow[rr];                                         \
            if (grow >= N) grow = N - 1;                                        \
            rg[rr] = *(const float4*)(x + (size_t)grow * IN_DIM +               \
                                      (c) * STAGE_K + scp * 4);                 \
        }                                                                       \
    }
    // WRITEC(buf): transpose rg into ldsT[buf]
#define WRITEC(buf)                                                             \
    {                                                                           \
        _Pragma("unroll")                                                       \
        for (int rr = 0; rr < 4; ++rr) {                                        \
            ldsT[buf][scp * 4 + 0][srow[rr]] = rg[rr].x;                        \
            ldsT[buf][scp * 4 + 1][srow[rr]] = rg[rr].y;                        \
            ldsT[buf][scp * 4 + 2][srow[rr]] = rg[rr].z;                        \
            ldsT[buf][scp * 4 + 3][srow[rr]] = rg[rr].w;                        \
        }                                                                       \
    }

    LOADC(0);
    WRITEC(0);
    for (int c = 0; c < NCHUNK; ++c) {
        if (c + 1 < NCHUNK) LOADC(c + 1);
        __syncthreads();                   // ldsT[c&1] ready
#pragma unroll
        for (int kk = 0; kk < STAGE_K; ++kk) {
            float xv = ldsT[c & 1][kk][t];
            const float* wr = W_in + (c * STAGE_K + kk) * HID + h * 32;  // uniform
#pragma unroll
            for (int jj = 0; jj < 32; ++jj)
                acc[jj] = fmaf(xv, wr[jj], acc[jj]);
        }
        __syncthreads();                   // all reads of ldsT[(c+1)&1] (from c-1) done
        if (c + 1 < NCHUNK) WRITEC((c + 1) & 1);
    }
#undef LOADC
#undef WRITEC

    float zv = 0.0f;
#pragma unroll
    for (int jj = 0; jj < 32; ++jj)
        zv = fmaf(fmaxf(acc[jj], 0.0f), weff_l[jj], zv);
    zpart[(size_t)h * Npad + node] = zv;
}

// ---------------- pass A: binned degree count (LDS atomics only) ----------------
__global__ __launch_bounds__(SCAN_TPB) void k_binA(const int* __restrict__ dst,
                                                   int* __restrict__ part,
                                                   int E, int chunk) {
    __shared__ int cnt[RANGE];
    for (int i = threadIdx.x; i < RANGE; i += SCAN_TPB) cnt[i] = 0;
    __syncthreads();

    const int r = blockIdx.x % NB;
    const int lo = r << RANGE_BITS;
    const int e0 = (blockIdx.x / NB) * chunk;
    const int e1 = min(E, e0 + chunk);
    for (int e = e0 + (int)threadIdx.x * 4; e + 3 < e1; e += SCAN_TPB * 4) {
        int4 d4 = *(const int4*)(dst + e);
        unsigned v;
        v = (unsigned)(d4.x - lo); if (v < RANGE) atomicAdd(&cnt[v], 1);
        v = (unsigned)(d4.y - lo); if (v < RANGE) atomicAdd(&cnt[v], 1);
        v = (unsigned)(d4.z - lo); if (v < RANGE) atomicAdd(&cnt[v], 1);
        v = (unsigned)(d4.w - lo); if (v < RANGE) atomicAdd(&cnt[v], 1);
    }
    __syncthreads();

    int* outp = part + (size_t)blockIdx.x * RANGE;
    for (int i = threadIdx.x; i < RANGE; i += SCAN_TPB) outp[i] = cnt[i];
}

// ---------------- reduce deg -> dinv, z = zpart0+zpart1, zs = z * dinv ----------------
__global__ __launch_bounds__(256) void k_redDeg(const int* __restrict__ part,
                                                const float* __restrict__ zpart,
                                                float* __restrict__ dinv,
                                                float* __restrict__ zs,
                                                int N, int Npad) {
    int i = blockIdx.x * blockDim.x + threadIdx.x;
    if (i >= N) return;
    const int r = i >> RANGE_BITS, idx = i & (RANGE - 1);
    int d = 0;
#pragma unroll 4
    for (int m = 0; m < MCH; ++m)
        d += part[((size_t)m * NB + r) * RANGE + idx];
    float di = rsqrtf((float)d + 1.0f);
    dinv[i] = di;
    zs[i]   = (zpart[i] + zpart[(size_t)Npad + i]) * di;
}

// ---------------- pass C: binned value scatter (LDS float atomics only) ----------------
__global__ __launch_bounds__(SCAN_TPB) void k_binC(const int* __restrict__ eidx,
                                                   const float* __restrict__ zs,
                                                   float* __restrict__ partf,
                                                   int E, int chunk) {
    __shared__ float acc[RANGE];
    for (int i = threadIdx.x; i < RANGE; i += SCAN_TPB) acc[i] = 0.0f;
    __syncthreads();

    const int r = blockIdx.x % NB;
    const int lo = r << RANGE_BITS;
    const int e0 = (blockIdx.x / NB) * chunk;
    const int e1 = min(E, e0 + chunk);
    for (int e = e0 + (int)threadIdx.x * 4; e + 3 < e1; e += SCAN_TPB * 4) {
        int4 s4 = *(const int4*)(eidx + e);        // src
        int4 d4 = *(const int4*)(eidx + E + e);    // dst
        unsigned v;
        v = (unsigned)(d4.x - lo); if (v < RANGE) atomicAdd(&acc[v], zs[s4.x]);
        v = (unsigned)(d4.y - lo); if (v < RANGE) atomicAdd(&acc[v], zs[s4.y]);
        v = (unsigned)(d4.z - lo); if (v < RANGE) atomicAdd(&acc[v], zs[s4.z]);
        v = (unsigned)(d4.w - lo); if (v < RANGE) atomicAdd(&acc[v], zs[s4.w]);
    }
    __syncthreads();

    float* outp = partf + (size_t)blockIdx.x * RANGE;
    for (int i = threadIdx.x; i < RANGE; i += SCAN_TPB) outp[i] = acc[i];
}

// ------- final: out = dinv * (sum partials + zs[self]) + (b_g.W_out + b_out) -------
__global__ __launch_bounds__(256) void k_redFinal(const float* __restrict__ partf,
                                                  const float* __restrict__ dinv,
                                                  const float* __restrict__ zs,
                                                  const float* __restrict__ b_g,
                                                  const float* __restrict__ W_out,
                                                  const float* __restrict__ b_out,
                                                  float* __restrict__ out, int N) {
    const int lane = threadIdx.x & 63;
    float c = b_g[lane] * W_out[lane];
#pragma unroll
    for (int off = 32; off > 0; off >>= 1)
        c += __shfl_xor(c, off, 64);
    c += b_out[0];

    int i = blockIdx.x * blockDim.x + threadIdx.x;
    if (i >= N) return;
    const int r = i >> RANGE_BITS, idx = i & (RANGE - 1);
    float a = zs[i];   // self-loop
#pragma unroll 4
    for (int m = 0; m < MCH; ++m)
        a += partf[((size_t)m * NB + r) * RANGE + idx];
    out[i] = fmaf(dinv[i], a, c);
}

// ---------------- launch ----------------

extern "C" void kernel_launch(void* const* d_in, const int* in_sizes, int n_in,
                              void* d_out, int out_size, void* d_ws, size_t ws_size,
                              hipStream_t stream) {
    const float* x     = (const float*)d_in[0];
    const int*   eidx  = (const int*)d_in[1];
    const float* W_in  = (const float*)d_in[2];
    const float* b_in  = (const float*)d_in[3];
    const float* W_g   = (const float*)d_in[4];
    const float* b_g   = (const float*)d_in[5];
    const float* W_out = (const float*)d_in[6];
    const float* b_out = (const float*)d_in[7];
    float* out = (float*)d_out;

    const int N = in_sizes[0] / IN_DIM;   // 100000
    const int E = in_sizes[1] / 2;        // 1600000

    // chunk: multiple of 4 covering E with MCH chunks
    const int chunk = (((E + MCH - 1) / MCH) + 3) & ~3;

    // ws layout: part[NB*MCH*RANGE] (int/float, reused) | zpart[2*Npad] | dinv[N] | zs[N]
    const size_t partElems = (size_t)NB * MCH * RANGE;
    const int Npad = (N + 63) & ~63;
    int*   part  = (int*)d_ws;
    float* partf = (float*)d_ws;          // reused after k_redDeg consumed counts
    float* zpart = (float*)d_ws + partElems;
    float* dinv  = zpart + 2 * (size_t)Npad;
    float* zs    = dinv + N;

    const int nG = (N + 255) / 256;       // node groups
    k_binA<<<NB * MCH, SCAN_TPB, 0, stream>>>(eidx + E, part, E, chunk);
    k_dense<<<nG * 2, 256, 0, stream>>>(x, W_in, b_in, W_g, W_out, zpart, N, Npad);
    k_redDeg<<<(N + 255) / 256, 256, 0, stream>>>(part, zpart, dinv, zs, N, Npad);
    k_binC<<<NB * MCH, SCAN_TPB, 0, stream>>>(eidx, zs, partf, E, chunk);
    k_redFinal<<<(N + 255) / 256, 256, 0, stream>>>(partf, dinv, zs, b_g, W_out, b_out, out, N);
}

// Round 17
// 93.053 us; speedup vs baseline: 2.0789x; 1.0424x over previous
//
#include <hip/hip_runtime.h>

#define HID 64
#define IN_DIM 128
// binC (float values)
#define RANGE_BITS 14
#define RANGE (1 << RANGE_BITS)   // 16384 nodes per 64 KB float bucket
#define NB 7
#define MCH 36
#define SCAN_TPB 512
// binA (packed u16 counters)
#define RB2 15
#define RANGE2 (1 << RB2)         // 32768 nodes per 64 KB u16 bucket
#define NB2 4
#define MCH2 36
// dense staging
#define SK 32                     // floats of each row per chunk (one full 128B line)
#define NCH (IN_DIM / SK)         // 4 chunks
#define LDSP 257

// ---------------- dense: block h-split, single-buffer LDS transpose, reg prefetch ----------------
// Block b: node group b>>1 (256 nodes), channel half h=b&1 (SGPR -> W scalar path).
// 4 chunks of [256 nodes][32 floats]; next chunk prefetched into registers during compute.
__global__ __launch_bounds__(256) void k_dense(const float* __restrict__ x,
                                               const float* __restrict__ W_in,
                                               const float* __restrict__ b_in,
                                               const float* __restrict__ W_g,
                                               const float* __restrict__ W_out,
                                               float* __restrict__ zpart,
                                               int N, int Npad) {
    const int g = blockIdx.x >> 1;
    const int h = blockIdx.x & 1;          // SGPR -> W addressing provably uniform

    __shared__ float weff_l[32];
    __shared__ float ldsT[SK][LDSP];       // 32.9 KB

    if (threadIdx.x < 32) {
        const int j = h * 32 + threadIdx.x;
        float s = 0.0f;
#pragma unroll
        for (int jp = 0; jp < HID; ++jp)
            s = fmaf(W_g[j * HID + jp], W_out[jp], s);
        weff_l[threadIdx.x] = s;
    }

    const int t = threadIdx.x;
    const int row0 = g * 256;
    int node = row0 + t;
    if (node >= N) node = N - 1;           // clamped threads duplicate-write identical values

    float acc[32];
#pragma unroll
    for (int jj = 0; jj < 32; ++jj)
        acc[jj] = b_in[h * 32 + jj];       // uniform -> s_load

    // staging: 8 float4/thread/chunk. seg s: row = s*32 + (t>>3), col = (t&7)*4.
    // Lanes 0..7 cover one full 128-B line -> perfect line consumption.
    float4 rg[8];
    const int lrow = t >> 3;               // 0..31
    const int lcol = (t & 7) * 4;          // 0,4,...,28

#define LOADC(c)                                                                 \
    {                                                                            \
        _Pragma("unroll")                                                        \
        for (int s = 0; s < 8; ++s) {                                            \
            int grow = row0 + s * 32 + lrow;                                     \
            if (grow >= N) grow = N - 1;                                         \
            rg[s] = *(const float4*)(x + (size_t)grow * IN_DIM + (c) * SK + lcol); \
        }                                                                        \
    }
#define WRITEC()                                                                 \
    {                                                                            \
        _Pragma("unroll")                                                        \
        for (int s = 0; s < 8; ++s) {                                            \
            ldsT[lcol + 0][s * 32 + lrow] = rg[s].x;                             \
            ldsT[lcol + 1][s * 32 + lrow] = rg[s].y;                             \
            ldsT[lcol + 2][s * 32 + lrow] = rg[s].z;                             \
            ldsT[lcol + 3][s * 32 + lrow] = rg[s].w;                             \
        }                                                                        \
    }

    LOADC(0);
    for (int c = 0; c < NCH; ++c) {
        WRITEC();                          // LDS <- rg (chunk c)
        __syncthreads();                   // writes visible
        if (c + 1 < NCH) LOADC(c + 1);     // global->reg, overlaps compute
#pragma unroll 8
        for (int kk = 0; kk < SK; ++kk) {
            float xv = ldsT[kk][t];        // conflict-free (consecutive t)
            const float* wr = W_in + (c * SK + kk) * HID + h * 32;  // uniform -> s_load
#pragma unroll
            for (int jj = 0; jj < 32; ++jj)
                acc[jj] = fmaf(xv, wr[jj], acc[jj]);
        }
        __syncthreads();                   // reads done before next WRITEC
    }
#undef LOADC
#undef WRITEC

    float zv = 0.0f;
#pragma unroll
    for (int jj = 0; jj < 32; ++jj)
        zv = fmaf(fmaxf(acc[jj], 0.0f), weff_l[jj], zv);
    zpart[(size_t)h * Npad + node] = zv;
}

// ---------------- pass A: binned degree count, packed u16 (LDS atomics only) ----------------
__global__ __launch_bounds__(SCAN_TPB) void k_binA(const int* __restrict__ dst,
                                                   unsigned* __restrict__ partA,
                                                   int E, int chunkA) {
    __shared__ unsigned cnt[RANGE2 / 2];   // 64 KB, 2 nodes per word
    for (int i = threadIdx.x; i < RANGE2 / 2; i += SCAN_TPB) cnt[i] = 0;
    __syncthreads();

    const int r = blockIdx.x % NB2;
    const int lo = r << RB2;
    const int e0 = (blockIdx.x / NB2) * chunkA;
    const int e1 = min(E, e0 + chunkA);
    for (int e = e0 + (int)threadIdx.x * 4; e + 3 < e1; e += SCAN_TPB * 4) {
        int4 d4 = *(const int4*)(dst + e);
        unsigned v;
        v = (unsigned)(d4.x - lo); if (v < RANGE2) atomicAdd(&cnt[v >> 1], 1u << ((v & 1) << 4));
        v = (unsigned)(d4.y - lo); if (v < RANGE2) atomicAdd(&cnt[v >> 1], 1u << ((v & 1) << 4));
        v = (unsigned)(d4.z - lo); if (v < RANGE2) atomicAdd(&cnt[v >> 1], 1u << ((v & 1) << 4));
        v = (unsigned)(d4.w - lo); if (v < RANGE2) atomicAdd(&cnt[v >> 1], 1u << ((v & 1) << 4));
    }
    __syncthreads();

    unsigned* outp = partA + (size_t)blockIdx.x * (RANGE2 / 2);
    for (int i = threadIdx.x; i < RANGE2 / 2; i += SCAN_TPB) outp[i] = cnt[i];
}

// ---------------- reduce deg (unpack u16) -> dinv, zs = (zpart0+zpart1) * dinv ----------------
__global__ __launch_bounds__(256) void k_redDeg(const unsigned* __restrict__ partA,
                                                const float* __restrict__ zpart,
                                                float* __restrict__ dinv,
                                                float* __restrict__ zs,
                                                int N, int Npad) {
    int i = blockIdx.x * blockDim.x + threadIdx.x;
    if (i >= N) return;
    const int r = i >> RB2, idx = i & (RANGE2 - 1);
    const int sh = (idx & 1) << 4;
    int d = 0;
#pragma unroll 4
    for (int m = 0; m < MCH2; ++m) {
        unsigned w = partA[((size_t)m * NB2 + r) * (RANGE2 / 2) + (idx >> 1)];
        d += (int)((w >> sh) & 0xFFFFu);
    }
    float di = rsqrtf((float)d + 1.0f);
    dinv[i] = di;
    zs[i]   = (zpart[i] + zpart[(size_t)Npad + i]) * di;
}

// ---------------- pass C: binned value scatter (LDS float atomics only) ----------------
__global__ __launch_bounds__(SCAN_TPB) void k_binC(const int* __restrict__ eidx,
                                                   const float* __restrict__ zs,
                                                   float* __restrict__ partf,
                                                   int E, int chunk) {
    __shared__ float acc[RANGE];
    for (int i = threadIdx.x; i < RANGE; i += SCAN_TPB) acc[i] = 0.0f;
    __syncthreads();

    const int r = blockIdx.x % NB;
    const int lo = r << RANGE_BITS;
    const int e0 = (blockIdx.x / NB) * chunk;
    const int e1 = min(E, e0 + chunk);
    for (int e = e0 + (int)threadIdx.x * 4; e + 3 < e1; e += SCAN_TPB * 4) {
        int4 s4 = *(const int4*)(eidx + e);        // src
        int4 d4 = *(const int4*)(eidx + E + e);    // dst
        unsigned v;
        v = (unsigned)(d4.x - lo); if (v < RANGE) atomicAdd(&acc[v], zs[s4.x]);
        v = (unsigned)(d4.y - lo); if (v < RANGE) atomicAdd(&acc[v], zs[s4.y]);
        v = (unsigned)(d4.z - lo); if (v < RANGE) atomicAdd(&acc[v], zs[s4.z]);
        v = (unsigned)(d4.w - lo); if (v < RANGE) atomicAdd(&acc[v], zs[s4.w]);
    }
    __syncthreads();

    float* outp = partf + (size_t)blockIdx.x * RANGE;
    for (int i = threadIdx.x; i < RANGE; i += SCAN_TPB) outp[i] = acc[i];
}

// ------- final: out = dinv * (sum partials + zs[self]) + (b_g.W_out + b_out) -------
__global__ __launch_bounds__(256) void k_redFinal(const float* __restrict__ partf,
                                                  const float* __restrict__ dinv,
                                                  const float* __restrict__ zs,
                                                  const float* __restrict__ b_g,
                                                  const float* __restrict__ W_out,
                                                  const float* __restrict__ b_out,
                                                  float* __restrict__ out, int N) {
    const int lane = threadIdx.x & 63;
    float c = b_g[lane] * W_out[lane];
#pragma unroll
    for (int off = 32; off > 0; off >>= 1)
        c += __shfl_xor(c, off, 64);
    c += b_out[0];

    int i = blockIdx.x * blockDim.x + threadIdx.x;
    if (i >= N) return;
    const int r = i >> RANGE_BITS, idx = i & (RANGE - 1);
    float a = zs[i];   // self-loop
#pragma unroll 4
    for (int m = 0; m < MCH; ++m)
        a += partf[((size_t)m * NB + r) * RANGE + idx];
    out[i] = fmaf(dinv[i], a, c);
}

// ---------------- launch ----------------

extern "C" void kernel_launch(void* const* d_in, const int* in_sizes, int n_in,
                              void* d_out, int out_size, void* d_ws, size_t ws_size,
                              hipStream_t stream) {
    const float* x     = (const float*)d_in[0];
    const int*   eidx  = (const int*)d_in[1];
    const float* W_in  = (const float*)d_in[2];
    const float* b_in  = (const float*)d_in[3];
    const float* W_g   = (const float*)d_in[4];
    const float* b_g   = (const float*)d_in[5];
    const float* W_out = (const float*)d_in[6];
    const float* b_out = (const float*)d_in[7];
    float* out = (float*)d_out;

    const int N = in_sizes[0] / IN_DIM;   // 100000
    const int E = in_sizes[1] / 2;        // 1600000

    // chunks: multiples of 4
    const int chunk  = (((E + MCH  - 1) / MCH ) + 3) & ~3;
    const int chunkA = (((E + MCH2 - 1) / MCH2) + 3) & ~3;

    // ws layout: region0 = max(partf 16.5MB, partA 9.4MB) | zpart[2*Npad] | dinv[N] | zs[N]
    const size_t partElems = (size_t)NB * MCH * RANGE;   // floats (>= binA's u32 words)
    const int Npad = (N + 63) & ~63;
    unsigned* partA = (unsigned*)d_ws;    // consumed by redDeg before binC overwrites
    float*    partf = (float*)d_ws;
    float*    zpart = (float*)d_ws + partElems;
    float*    dinv  = zpart + 2 * (size_t)Npad;
    float*    zs    = dinv + N;

    const int nG = (N + 255) / 256;       // node groups
    k_binA<<<NB2 * MCH2, SCAN_TPB, 0, stream>>>(eidx + E, partA, E, chunkA);
    k_dense<<<nG * 2, 256, 0, stream>>>(x, W_in, b_in, W_g, W_out, zpart, N, Npad);
    k_redDeg<<<(N + 255) / 256, 256, 0, stream>>>(partA, zpart, dinv, zs, N, Npad);
    k_binC<<<NB * MCH, SCAN_TPB, 0, stream>>>(eidx, zs, partf, E, chunk);
    k_redFinal<<<(N + 255) / 256, 256, 0, stream>>>(partf, dinv, zs, b_g, W_out, b_out, out, N);
}

// Round 18
// 90.226 us; speedup vs baseline: 2.1441x; 1.0313x over previous
//
#include <hip/hip_runtime.h>

#define HID 64
#define IN_DIM 128
// binC (float values)
#define RANGE_BITS 14
#define RANGE (1 << RANGE_BITS)   // 16384 nodes per 64 KB float bucket
#define NB 7
#define MCH 36
#define SCAN_TPB 512
// binA (packed u16 counters)
#define RB2 15
#define RANGE2 (1 << RB2)         // 32768 nodes per 64 KB u16 bucket
#define NB2 4
#define MCH2 64
// dense staging
#define DB 128                    // dense block threads = nodes per block
#define SK 32                     // floats of each row per chunk (one full 128B line)
#define NCH (IN_DIM / SK)         // 4 chunks
#define LDSP (DB + 1)             // 129

// ---------------- dense: 128-node blocks, h-split by blockIdx, LDS transpose ----------------
// Block b: node group b>>1 (128 nodes), channel half h=b&1 (SGPR -> W scalar path).
// 4 chunks of [128 nodes][32 floats]; next chunk prefetched into registers during compute.
__global__ __launch_bounds__(DB) void k_dense(const float* __restrict__ x,
                                              const float* __restrict__ W_in,
                                              const float* __restrict__ b_in,
                                              const float* __restrict__ W_g,
                                              const float* __restrict__ W_out,
                                              float* __restrict__ zpart,
                                              int N, int Npad) {
    const int g = blockIdx.x >> 1;
    const int h = blockIdx.x & 1;          // SGPR -> W addressing provably uniform

    __shared__ float weff_l[32];
    __shared__ float ldsT[SK][LDSP];       // 16.5 KB

    if (threadIdx.x < 32) {
        const int j = h * 32 + threadIdx.x;
        float s = 0.0f;
#pragma unroll
        for (int jp = 0; jp < HID; ++jp)
            s = fmaf(W_g[j * HID + jp], W_out[jp], s);
        weff_l[threadIdx.x] = s;
    }

    const int t = threadIdx.x;
    const int row0 = g * DB;
    int node = row0 + t;
    if (node >= N) node = N - 1;           // clamped threads duplicate-write identical values

    float acc[32];
#pragma unroll
    for (int jj = 0; jj < 32; ++jj)
        acc[jj] = b_in[h * 32 + jj];       // uniform -> s_load

    // staging: 8 float4/thread/chunk. seg s: row = s*16 + (t>>3), col = (t&7)*4.
    // 8 lanes cover one full 128-B line -> perfect line consumption.
    float4 rg[8];
    const int lrow = t >> 3;               // 0..15
    const int lcol = (t & 7) * 4;          // 0,4,...,28

#define LOADC(c)                                                                 \
    {                                                                            \
        _Pragma("unroll")                                                        \
        for (int s = 0; s < 8; ++s) {                                            \
            int grow = row0 + s * 16 + lrow;                                     \
            if (grow >= N) grow = N - 1;                                         \
            rg[s] = *(const float4*)(x + (size_t)grow * IN_DIM + (c) * SK + lcol); \
        }                                                                        \
    }
#define WRITEC()                                                                 \
    {                                                                            \
        _Pragma("unroll")                                                        \
        for (int s = 0; s < 8; ++s) {                                            \
            ldsT[lcol + 0][s * 16 + lrow] = rg[s].x;                             \
            ldsT[lcol + 1][s * 16 + lrow] = rg[s].y;                             \
            ldsT[lcol + 2][s * 16 + lrow] = rg[s].z;                             \
            ldsT[lcol + 3][s * 16 + lrow] = rg[s].w;                             \
        }                                                                        \
    }

    LOADC(0);
    for (int c = 0; c < NCH; ++c) {
        WRITEC();                          // LDS <- rg (chunk c)
        __syncthreads();                   // writes visible
        if (c + 1 < NCH) LOADC(c + 1);     // global->reg, overlaps compute
#pragma unroll 8
        for (int kk = 0; kk < SK; ++kk) {
            float xv = ldsT[kk][t];        // conflict-free (consecutive t)
            const float* wr = W_in + (c * SK + kk) * HID + h * 32;  // uniform -> s_load
#pragma unroll
            for (int jj = 0; jj < 32; ++jj)
                acc[jj] = fmaf(xv, wr[jj], acc[jj]);
        }
        __syncthreads();                   // reads done before next WRITEC
    }
#undef LOADC
#undef WRITEC

    float zv = 0.0f;
#pragma unroll
    for (int jj = 0; jj < 32; ++jj)
        zv = fmaf(fmaxf(acc[jj], 0.0f), weff_l[jj], zv);
    zpart[(size_t)h * Npad + node] = zv;
}

// ---------------- pass A: binned degree count, packed u16 (LDS atomics only) ----------------
__global__ __launch_bounds__(SCAN_TPB) void k_binA(const int* __restrict__ dst,
                                                   unsigned* __restrict__ partA,
                                                   int E, int chunkA) {
    __shared__ unsigned cnt[RANGE2 / 2];   // 64 KB, 2 nodes per word
    for (int i = threadIdx.x; i < RANGE2 / 2; i += SCAN_TPB) cnt[i] = 0;
    __syncthreads();

    const int r = blockIdx.x % NB2;
    const int lo = r << RB2;
    const int e0 = (blockIdx.x / NB2) * chunkA;
    const int e1 = min(E, e0 + chunkA);
    for (int e = e0 + (int)threadIdx.x * 4; e + 3 < e1; e += SCAN_TPB * 4) {
        int4 d4 = *(const int4*)(dst + e);
        unsigned v;
        v = (unsigned)(d4.x - lo); if (v < RANGE2) atomicAdd(&cnt[v >> 1], 1u << ((v & 1) << 4));
        v = (unsigned)(d4.y - lo); if (v < RANGE2) atomicAdd(&cnt[v >> 1], 1u << ((v & 1) << 4));
        v = (unsigned)(d4.z - lo); if (v < RANGE2) atomicAdd(&cnt[v >> 1], 1u << ((v & 1) << 4));
        v = (unsigned)(d4.w - lo); if (v < RANGE2) atomicAdd(&cnt[v >> 1], 1u << ((v & 1) << 4));
    }
    __syncthreads();

    unsigned* outp = partA + (size_t)blockIdx.x * (RANGE2 / 2);
    for (int i = threadIdx.x; i < RANGE2 / 2; i += SCAN_TPB) outp[i] = cnt[i];
}

// ---------------- reduce deg (unpack u16) -> dinv, zs = (zpart0+zpart1) * dinv ----------------
__global__ __launch_bounds__(256) void k_redDeg(const unsigned* __restrict__ partA,
                                                const float* __restrict__ zpart,
                                                float* __restrict__ dinv,
                                                float* __restrict__ zs,
                                                int N, int Npad) {
    int i = blockIdx.x * blockDim.x + threadIdx.x;
    if (i >= N) return;
    const int r = i >> RB2, idx = i & (RANGE2 - 1);
    const int sh = (idx & 1) << 4;
    int d = 0;
#pragma unroll 4
    for (int m = 0; m < MCH2; ++m) {
        unsigned w = partA[((size_t)m * NB2 + r) * (RANGE2 / 2) + (idx >> 1)];
        d += (int)((w >> sh) & 0xFFFFu);
    }
    float di = rsqrtf((float)d + 1.0f);
    dinv[i] = di;
    zs[i]   = (zpart[i] + zpart[(size_t)Npad + i]) * di;
}

// ---------------- pass C: binned value scatter (LDS float atomics only) ----------------
__global__ __launch_bounds__(SCAN_TPB) void k_binC(const int* __restrict__ eidx,
                                                   const float* __restrict__ zs,
                                                   float* __restrict__ partf,
                                                   int E, int chunk) {
    __shared__ float acc[RANGE];
    for (int i = threadIdx.x; i < RANGE; i += SCAN_TPB) acc[i] = 0.0f;
    __syncthreads();

    const int r = blockIdx.x % NB;
    const int lo = r << RANGE_BITS;
    const int e0 = (blockIdx.x / NB) * chunk;
    const int e1 = min(E, e0 + chunk);
    for (int e = e0 + (int)threadIdx.x * 4; e + 3 < e1; e += SCAN_TPB * 4) {
        int4 s4 = *(const int4*)(eidx + e);        // src
        int4 d4 = *(const int4*)(eidx + E + e);    // dst
        unsigned v;
        v = (unsigned)(d4.x - lo); if (v < RANGE) atomicAdd(&acc[v], zs[s4.x]);
        v = (unsigned)(d4.y - lo); if (v < RANGE) atomicAdd(&acc[v], zs[s4.y]);
        v = (unsigned)(d4.z - lo); if (v < RANGE) atomicAdd(&acc[v], zs[s4.z]);
        v = (unsigned)(d4.w - lo); if (v < RANGE) atomicAdd(&acc[v], zs[s4.w]);
    }
    __syncthreads();

    float* outp = partf + (size_t)blockIdx.x * RANGE;
    for (int i = threadIdx.x; i < RANGE; i += SCAN_TPB) outp[i] = acc[i];
}

// ------- final: out = dinv * (sum partials + zs[self]) + (b_g.W_out + b_out) -------
__global__ __launch_bounds__(256) void k_redFinal(const float* __restrict__ partf,
                                                  const float* __restrict__ dinv,
                                                  const float* __restrict__ zs,
                                                  const float* __restrict__ b_g,
                                                  const float* __restrict__ W_out,
                                                  const float* __restrict__ b_out,
                                                  float* __restrict__ out, int N) {
    const int lane = threadIdx.x & 63;
    float c = b_g[lane] * W_out[lane];
#pragma unroll
    for (int off = 32; off > 0; off >>= 1)
        c += __shfl_xor(c, off, 64);
    c += b_out[0];

    int i = blockIdx.x * blockDim.x + threadIdx.x;
    if (i >= N) return;
    const int r = i >> RANGE_BITS, idx = i & (RANGE - 1);
    float a = zs[i];   // self-loop
#pragma unroll 4
    for (int m = 0; m < MCH; ++m)
        a += partf[((size_t)m * NB + r) * RANGE + idx];
    out[i] = fmaf(dinv[i], a, c);
}

// ---------------- launch ----------------

extern "C" void kernel_launch(void* const* d_in, const int* in_sizes, int n_in,
                              void* d_out, int out_size, void* d_ws, size_t ws_size,
                              hipStream_t stream) {
    const float* x     = (const float*)d_in[0];
    const int*   eidx  = (const int*)d_in[1];
    const float* W_in  = (const float*)d_in[2];
    const float* b_in  = (const float*)d_in[3];
    const float* W_g   = (const float*)d_in[4];
    const float* b_g   = (const float*)d_in[5];
    const float* W_out = (const float*)d_in[6];
    const float* b_out = (const float*)d_in[7];
    float* out = (float*)d_out;

    const int N = in_sizes[0] / IN_DIM;   // 100000
    const int E = in_sizes[1] / 2;        // 1600000

    // chunks: multiples of 4
    const int chunk  = (((E + MCH  - 1) / MCH ) + 3) & ~3;
    const int chunkA = (((E + MCH2 - 1) / MCH2) + 3) & ~3;

    // ws layout: region0 = max(partf 16.5MB, partA 16.8MB u32) | zpart[2*Npad] | dinv[N] | zs[N]
    const size_t partElems0 = (size_t)NB * MCH * RANGE;              // binC floats
    const size_t partElemsA = (size_t)NB2 * MCH2 * (RANGE2 / 2);     // binA u32 words
    const size_t partElems = partElems0 > partElemsA ? partElems0 : partElemsA;
    const int Npad = (N + 63) & ~63;
    unsigned* partA = (unsigned*)d_ws;    // consumed by redDeg before binC overwrites
    float*    partf = (float*)d_ws;
    float*    zpart = (float*)d_ws + partElems;
    float*    dinv  = zpart + 2 * (size_t)Npad;
    float*    zs    = dinv + N;

    const int nG = (N + DB - 1) / DB;     // node groups (128 nodes each)
    k_binA<<<NB2 * MCH2, SCAN_TPB, 0, stream>>>(eidx + E, partA, E, chunkA);
    k_dense<<<nG * 2, DB, 0, stream>>>(x, W_in, b_in, W_g, W_out, zpart, N, Npad);
    k_redDeg<<<(N + 255) / 256, 256, 0, stream>>>(partA, zpart, dinv, zs, N, Npad);
    k_binC<<<NB * MCH, SCAN_TPB, 0, stream>>>(eidx, zs, partf, E, chunk);
    k_redFinal<<<(N + 255) / 256, 256, 0, stream>>>(partf, dinv, zs, b_g, W_out, b_out, out, N);
}

// Round 19
// 86.692 us; speedup vs baseline: 2.2315x; 1.0408x over previous
//
#include <hip/hip_runtime.h>

#define HID 64
#define IN_DIM 128
// binC (float values)
#define RANGE_BITS 14
#define RANGE (1 << RANGE_BITS)   // 16384 nodes per 64 KB float bucket
#define NB 7
#define MCH 36
#define SCAN_TPB 512
// binA (packed u16 counters)
#define RB2 15
#define RANGE2 (1 << RB2)         // 32768 nodes per 64 KB u16 bucket
#define NB2 4
#define MCH2 64
// dense staging
#define SK 32                     // floats of each row per chunk (one full 128B line)
#define NCH (IN_DIM / SK)         // 4 chunks
#define LDSP 129                  // padded node-stride in LDS tile

// ---------------- dense: 256-thread block, 128 nodes, both halves, single staging ----------------
// Wave w: channel half h=w>>1 (forced SGPR via readfirstlane), nodes (w&1)*64+lane.
// x chunk staged ONCE per block, consumed by all 4 waves. W on scalar/K$ path.
__global__ __launch_bounds__(256) void k_dense(const float* __restrict__ x,
                                               const float* __restrict__ W_in,
                                               const float* __restrict__ b_in,
                                               const float* __restrict__ W_g,
                                               const float* __restrict__ W_out,
                                               float* __restrict__ zpart,
                                               int N, int Npad) {
    __shared__ float weff_l[HID];
    __shared__ float ldsT[SK][LDSP];       // 16.5 KB

    const int t = threadIdx.x;
    if (t < HID) {
        float s = 0.0f;
#pragma unroll
        for (int jp = 0; jp < HID; ++jp)
            s = fmaf(W_g[t * HID + jp], W_out[jp], s);
        weff_l[t] = s;
    }

    const int h = __builtin_amdgcn_readfirstlane(t >> 7);  // wave-uniform -> SGPR
    const int nidx = t & 127;              // node within block
    const int row0 = blockIdx.x * 128;
    int node = row0 + nidx;
    if (node >= N) node = N - 1;           // clamped threads duplicate-write identical values

    float acc[32];
#pragma unroll
    for (int jj = 0; jj < 32; ++jj)
        acc[jj] = b_in[h * 32 + jj];       // uniform -> s_load

    // staging: 4 float4/thread/chunk. seg s: row = s*32 + (t>>3), col = (t&7)*4.
    // 8 lanes cover one full 128-B line -> perfect line consumption.
    float4 rg[4];
    const int lrow = t >> 3;               // 0..31
    const int lcol = (t & 7) * 4;          // 0,4,...,28

#define LOADC(c)                                                                 \
    {                                                                            \
        _Pragma("unroll")                                                        \
        for (int s = 0; s < 4; ++s) {                                            \
            int grow = row0 + s * 32 + lrow;                                     \
            if (grow >= N) grow = N - 1;                                         \
            rg[s] = *(const float4*)(x + (size_t)grow * IN_DIM + (c) * SK + lcol); \
        }                                                                        \
    }
#define WRITEC()                                                                 \
    {                                                                            \
        _Pragma("unroll")                                                        \
        for (int s = 0; s < 4; ++s) {                                            \
            ldsT[lcol + 0][s * 32 + lrow] = rg[s].x;                             \
            ldsT[lcol + 1][s * 32 + lrow] = rg[s].y;                             \
            ldsT[lcol + 2][s * 32 + lrow] = rg[s].z;                             \
            ldsT[lcol + 3][s * 32 + lrow] = rg[s].w;                             \
        }                                                                        \
    }

    LOADC(0);
    for (int c = 0; c < NCH; ++c) {
        WRITEC();                          // LDS <- rg (chunk c)
        __syncthreads();                   // writes visible (also covers weff_l)
        if (c + 1 < NCH) LOADC(c + 1);     // global->reg, overlaps compute
#pragma unroll 8
        for (int kk = 0; kk < SK; ++kk) {
            float xv = ldsT[kk][nidx];     // consecutive lanes -> conflict-free
            const float* wr = W_in + (c * SK + kk) * HID + h * 32;  // uniform -> s_load
#pragma unroll
            for (int jj = 0; jj < 32; ++jj)
                acc[jj] = fmaf(xv, wr[jj], acc[jj]);
        }
        __syncthreads();                   // reads done before next WRITEC
    }
#undef LOADC
#undef WRITEC

    float zv = 0.0f;
#pragma unroll
    for (int jj = 0; jj < 32; ++jj)
        zv = fmaf(fmaxf(acc[jj], 0.0f), weff_l[h * 32 + jj], zv);
    zpart[(size_t)h * Npad + node] = zv;
}

// ---------------- pass A: binned degree count, packed u16 (LDS atomics only) ----------------
__global__ __launch_bounds__(SCAN_TPB) void k_binA(const int* __restrict__ dst,
                                                   unsigned* __restrict__ partA,
                                                   int E, int chunkA) {
    __shared__ unsigned cnt[RANGE2 / 2];   // 64 KB, 2 nodes per word
    for (int i = threadIdx.x; i < RANGE2 / 2; i += SCAN_TPB) cnt[i] = 0;
    __syncthreads();

    const int r = blockIdx.x % NB2;
    const int lo = r << RB2;
    const int e0 = (blockIdx.x / NB2) * chunkA;
    const int e1 = min(E, e0 + chunkA);
    for (int e = e0 + (int)threadIdx.x * 4; e + 3 < e1; e += SCAN_TPB * 4) {
        int4 d4 = *(const int4*)(dst + e);
        unsigned v;
        v = (unsigned)(d4.x - lo); if (v < RANGE2) atomicAdd(&cnt[v >> 1], 1u << ((v & 1) << 4));
        v = (unsigned)(d4.y - lo); if (v < RANGE2) atomicAdd(&cnt[v >> 1], 1u << ((v & 1) << 4));
        v = (unsigned)(d4.z - lo); if (v < RANGE2) atomicAdd(&cnt[v >> 1], 1u << ((v & 1) << 4));
        v = (unsigned)(d4.w - lo); if (v < RANGE2) atomicAdd(&cnt[v >> 1], 1u << ((v & 1) << 4));
    }
    __syncthreads();

    unsigned* outp = partA + (size_t)blockIdx.x * (RANGE2 / 2);
    for (int i = threadIdx.x; i < RANGE2 / 2; i += SCAN_TPB) outp[i] = cnt[i];
}

// ---------------- reduce deg (unpack u16) -> dinv, zs = (zpart0+zpart1) * dinv ----------------
__global__ __launch_bounds__(256) void k_redDeg(const unsigned* __restrict__ partA,
                                                const float* __restrict__ zpart,
                                                float* __restrict__ dinv,
                                                float* __restrict__ zs,
                                                int N, int Npad) {
    int i = blockIdx.x * blockDim.x + threadIdx.x;
    if (i >= N) return;
    const int r = i >> RB2, idx = i & (RANGE2 - 1);
    const int sh = (idx & 1) << 4;
    int d = 0;
#pragma unroll 4
    for (int m = 0; m < MCH2; ++m) {
        unsigned w = partA[((size_t)m * NB2 + r) * (RANGE2 / 2) + (idx >> 1)];
        d += (int)((w >> sh) & 0xFFFFu);
    }
    float di = rsqrtf((float)d + 1.0f);
    dinv[i] = di;
    zs[i]   = (zpart[i] + zpart[(size_t)Npad + i]) * di;
}

// ---------------- pass C: binned value scatter (LDS float atomics only) ----------------
__global__ __launch_bounds__(SCAN_TPB) void k_binC(const int* __restrict__ eidx,
                                                   const float* __restrict__ zs,
                                                   float* __restrict__ partf,
                                                   int E, int chunk) {
    __shared__ float acc[RANGE];
    for (int i = threadIdx.x; i < RANGE; i += SCAN_TPB) acc[i] = 0.0f;
    __syncthreads();

    const int r = blockIdx.x % NB;
    const int lo = r << RANGE_BITS;
    const int e0 = (blockIdx.x / NB) * chunk;
    const int e1 = min(E, e0 + chunk);
    for (int e = e0 + (int)threadIdx.x * 4; e + 3 < e1; e += SCAN_TPB * 4) {
        int4 s4 = *(const int4*)(eidx + e);        // src
        int4 d4 = *(const int4*)(eidx + E + e);    // dst
        unsigned v;
        v = (unsigned)(d4.x - lo); if (v < RANGE) atomicAdd(&acc[v], zs[s4.x]);
        v = (unsigned)(d4.y - lo); if (v < RANGE) atomicAdd(&acc[v], zs[s4.y]);
        v = (unsigned)(d4.z - lo); if (v < RANGE) atomicAdd(&acc[v], zs[s4.z]);
        v = (unsigned)(d4.w - lo); if (v < RANGE) atomicAdd(&acc[v], zs[s4.w]);
    }
    __syncthreads();

    float* outp = partf + (size_t)blockIdx.x * RANGE;
    for (int i = threadIdx.x; i < RANGE; i += SCAN_TPB) outp[i] = acc[i];
}

// ------- final: out = dinv * (sum partials + zs[self]) + (b_g.W_out + b_out) -------
__global__ __launch_bounds__(256) void k_redFinal(const float* __restrict__ partf,
                                                  const float* __restrict__ dinv,
                                                  const float* __restrict__ zs,
                                                  const float* __restrict__ b_g,
                                                  const float* __restrict__ W_out,
                                                  const float* __restrict__ b_out,
                                                  float* __restrict__ out, int N) {
    const int lane = threadIdx.x & 63;
    float c = b_g[lane] * W_out[lane];
#pragma unroll
    for (int off = 32; off > 0; off >>= 1)
        c += __shfl_xor(c, off, 64);
    c += b_out[0];

    int i = blockIdx.x * blockDim.x + threadIdx.x;
    if (i >= N) return;
    const int r = i >> RANGE_BITS, idx = i & (RANGE - 1);
    float a = zs[i];   // self-loop
#pragma unroll 4
    for (int m = 0; m < MCH; ++m)
        a += partf[((size_t)m * NB + r) * RANGE + idx];
    out[i] = fmaf(dinv[i], a, c);
}

// ---------------- launch ----------------

extern "C" void kernel_launch(void* const* d_in, const int* in_sizes, int n_in,
                              void* d_out, int out_size, void* d_ws, size_t ws_size,
                              hipStream_t stream) {
    const float* x     = (const float*)d_in[0];
    const int*   eidx  = (const int*)d_in[1];
    const float* W_in  = (const float*)d_in[2];
    const float* b_in  = (const float*)d_in[3];
    const float* W_g   = (const float*)d_in[4];
    const float* b_g   = (const float*)d_in[5];
    const float* W_out = (const float*)d_in[6];
    const float* b_out = (const float*)d_in[7];
    float* out = (float*)d_out;

    const int N = in_sizes[0] / IN_DIM;   // 100000
    const int E = in_sizes[1] / 2;        // 1600000

    // chunks: multiples of 4
    const int chunk  = (((E + MCH  - 1) / MCH ) + 3) & ~3;
    const int chunkA = (((E + MCH2 - 1) / MCH2) + 3) & ~3;

    // ws layout: region0 = max(partf 16.5MB, partA 16.8MB u32) | zpart[2*Npad] | dinv[N] | zs[N]
    const size_t partElems0 = (size_t)NB * MCH * RANGE;              // binC floats
    const size_t partElemsA = (size_t)NB2 * MCH2 * (RANGE2 / 2);     // binA u32 words
    const size_t partElems = partElems0 > partElemsA ? partElems0 : partElemsA;
    const int Npad = (N + 63) & ~63;
    unsigned* partA = (unsigned*)d_ws;    // consumed by redDeg before binC overwrites
    float*    partf = (float*)d_ws;
    float*    zpart = (float*)d_ws + partElems;
    float*    dinv  = zpart + 2 * (size_t)Npad;
    float*    zs    = dinv + N;

    const int nG = (N + 127) / 128;       // node groups (128 nodes each)
    k_binA<<<NB2 * MCH2, SCAN_TPB, 0, stream>>>(eidx + E, partA, E, chunkA);
    k_dense<<<nG, 256, 0, stream>>>(x, W_in, b_in, W_g, W_out, zpart, N, Npad);
    k_redDeg<<<(N + 255) / 256, 256, 0, stream>>>(partA, zpart, dinv, zs, N, Npad);
    k_binC<<<NB * MCH, SCAN_TPB, 0, stream>>>(eidx, zs, partf, E, chunk);
    k_redFinal<<<(N + 255) / 256, 256, 0, stream>>>(partf, dinv, zs, b_g, W_out, b_out, out, N);
}

// Round 20
// 82.560 us; speedup vs baseline: 2.3432x; 1.0501x over previous
//
#include <hip/hip_runtime.h>

#define HID 64
#define IN_DIM 128
// binC (float values)
#define RANGE_BITS 14
#define RANGE (1 << RANGE_BITS)   // 16384 nodes per 64 KB float bucket
#define NB 7
#define MCH 36
#define SCAN_TPB 512
// binA (packed u16 counters)
#define RB2 15
#define RANGE2 (1 << RB2)         // 32768 nodes per 64 KB u16 bucket
#define NB2 4
#define MCH2 64
// dense staging
#define DNODES 64                 // nodes per dense block
#define SK 32                     // floats of each row per chunk (one full 128B line)
#define NCH (IN_DIM / SK)         // 4 chunks
#define LDSP (DNODES + 1)         // 65

// ---------------- dense: 64-node blocks, 4 channel-quarters (one per wave) ----------------
// Wave w: channel quarter q=w (SGPR via readfirstlane -> W scalar path), lane = node.
// x chunk staged once per block (8.3 KB LDS), consumed by all 4 waves.
// Grid = 1563 blocks -> ~6 blocks/CU -> ~24 waves/CU.
__global__ __launch_bounds__(256) void k_dense(const float* __restrict__ x,
                                               const float* __restrict__ W_in,
                                               const float* __restrict__ b_in,
                                               const float* __restrict__ W_g,
                                               const float* __restrict__ W_out,
                                               float* __restrict__ zpart,
                                               int N, int Npad) {
    __shared__ float weff_l[HID];
    __shared__ float ldsT[SK][LDSP];       // 8.3 KB

    const int t = threadIdx.x;

    // lane-parallel w_eff = W_g @ W_out: thread t -> j = t>>2, jp block = (t&3)*16
    {
        const float* wg = W_g + (t >> 2) * HID + (t & 3) * 16;   // coalesced 64B/4lanes
        const float* wo = W_out + (t & 3) * 16;
        float s = 0.0f;
#pragma unroll
        for (int p = 0; p < 16; ++p) s = fmaf(wg[p], wo[p], s);
        s += __shfl_xor(s, 1, 64);
        s += __shfl_xor(s, 2, 64);
        if ((t & 3) == 0) weff_l[t >> 2] = s;
    }

    const int q = __builtin_amdgcn_readfirstlane(t >> 6);  // channel quarter 0..3 (SGPR)
    const int nidx = t & 63;               // node within block
    const int row0 = blockIdx.x * DNODES;
    int node = row0 + nidx;
    if (node >= N) node = N - 1;           // clamped threads duplicate-write identical values

    float acc[16];
#pragma unroll
    for (int jj = 0; jj < 16; ++jj)
        acc[jj] = b_in[q * 16 + jj];       // uniform -> s_load

    // staging: 2 float4/thread/chunk. seg s: row = s*32 + (t>>3), col = (t&7)*4.
    // 8 lanes cover one full 128-B line -> perfect line consumption.
    float4 rg[2];
    const int lrow = t >> 3;               // 0..31
    const int lcol = (t & 7) * 4;          // 0,4,...,28

#define LOADC(c)                                                                 \
    {                                                                            \
        _Pragma("unroll")                                                        \
        for (int s = 0; s < 2; ++s) {                                            \
            int grow = row0 + s * 32 + lrow;                                     \
            if (grow >= N) grow = N - 1;                                         \
            rg[s] = *(const float4*)(x + (size_t)grow * IN_DIM + (c) * SK + lcol); \
        }                                                                        \
    }
#define WRITEC()                                                                 \
    {                                                                            \
        _Pragma("unroll")                                                        \
        for (int s = 0; s < 2; ++s) {                                            \
            ldsT[lcol + 0][s * 32 + lrow] = rg[s].x;                             \
            ldsT[lcol + 1][s * 32 + lrow] = rg[s].y;                             \
            ldsT[lcol + 2][s * 32 + lrow] = rg[s].z;                             \
            ldsT[lcol + 3][s * 32 + lrow] = rg[s].w;                             \
        }                                                                        \
    }

    LOADC(0);
    for (int c = 0; c < NCH; ++c) {
        WRITEC();                          // LDS <- rg (chunk c)
        __syncthreads();                   // writes visible (also covers weff_l)
        if (c + 1 < NCH) LOADC(c + 1);     // global->reg, overlaps compute
#pragma unroll 8
        for (int kk = 0; kk < SK; ++kk) {
            float xv = ldsT[kk][nidx];     // consecutive lanes -> conflict-free
            const float* wr = W_in + (c * SK + kk) * HID + q * 16;  // uniform -> s_load
#pragma unroll
            for (int jj = 0; jj < 16; ++jj)
                acc[jj] = fmaf(xv, wr[jj], acc[jj]);
        }
        __syncthreads();                   // reads done before next WRITEC
    }
#undef LOADC
#undef WRITEC

    float zv = 0.0f;
#pragma unroll
    for (int jj = 0; jj < 16; ++jj)
        zv = fmaf(fmaxf(acc[jj], 0.0f), weff_l[q * 16 + jj], zv);
    zpart[(size_t)q * Npad + node] = zv;
}

// ---------------- pass A: binned degree count, packed u16 (LDS atomics only) ----------------
__global__ __launch_bounds__(SCAN_TPB) void k_binA(const int* __restrict__ dst,
                                                   unsigned* __restrict__ partA,
                                                   int E, int chunkA) {
    __shared__ unsigned cnt[RANGE2 / 2];   // 64 KB, 2 nodes per word
    for (int i = threadIdx.x; i < RANGE2 / 2; i += SCAN_TPB) cnt[i] = 0;
    __syncthreads();

    const int r = blockIdx.x % NB2;
    const int lo = r << RB2;
    const int e0 = (blockIdx.x / NB2) * chunkA;
    const int e1 = min(E, e0 + chunkA);
    for (int e = e0 + (int)threadIdx.x * 4; e + 3 < e1; e += SCAN_TPB * 4) {
        int4 d4 = *(const int4*)(dst + e);
        unsigned v;
        v = (unsigned)(d4.x - lo); if (v < RANGE2) atomicAdd(&cnt[v >> 1], 1u << ((v & 1) << 4));
        v = (unsigned)(d4.y - lo); if (v < RANGE2) atomicAdd(&cnt[v >> 1], 1u << ((v & 1) << 4));
        v = (unsigned)(d4.z - lo); if (v < RANGE2) atomicAdd(&cnt[v >> 1], 1u << ((v & 1) << 4));
        v = (unsigned)(d4.w - lo); if (v < RANGE2) atomicAdd(&cnt[v >> 1], 1u << ((v & 1) << 4));
    }
    __syncthreads();

    unsigned* outp = partA + (size_t)blockIdx.x * (RANGE2 / 2);
    for (int i = threadIdx.x; i < RANGE2 / 2; i += SCAN_TPB) outp[i] = cnt[i];
}

// ------- reduce deg (unpack u16) -> dinv, zs = (zpart0+zpart1+zpart2+zpart3) * dinv -------
__global__ __launch_bounds__(256) void k_redDeg(const unsigned* __restrict__ partA,
                                                const float* __restrict__ zpart,
                                                float* __restrict__ dinv,
                                                float* __restrict__ zs,
                                                int N, int Npad) {
    int i = blockIdx.x * blockDim.x + threadIdx.x;
    if (i >= N) return;
    const int r = i >> RB2, idx = i & (RANGE2 - 1);
    const int sh = (idx & 1) << 4;
    int d = 0;
#pragma unroll 4
    for (int m = 0; m < MCH2; ++m) {
        unsigned w = partA[((size_t)m * NB2 + r) * (RANGE2 / 2) + (idx >> 1)];
        d += (int)((w >> sh) & 0xFFFFu);
    }
    float di = rsqrtf((float)d + 1.0f);
    dinv[i] = di;
    float z = zpart[i] + zpart[(size_t)Npad + i]
            + zpart[2 * (size_t)Npad + i] + zpart[3 * (size_t)Npad + i];
    zs[i] = z * di;
}

// ---------------- pass C: binned value scatter (LDS float atomics only) ----------------
__global__ __launch_bounds__(SCAN_TPB) void k_binC(const int* __restrict__ eidx,
                                                   const float* __restrict__ zs,
                                                   float* __restrict__ partf,
                                                   int E, int chunk) {
    __shared__ float acc[RANGE];
    for (int i = threadIdx.x; i < RANGE; i += SCAN_TPB) acc[i] = 0.0f;
    __syncthreads();

    const int r = blockIdx.x % NB;
    const int lo = r << RANGE_BITS;
    const int e0 = (blockIdx.x / NB) * chunk;
    const int e1 = min(E, e0 + chunk);
    for (int e = e0 + (int)threadIdx.x * 4; e + 3 < e1; e += SCAN_TPB * 4) {
        int4 s4 = *(const int4*)(eidx + e);        // src
        int4 d4 = *(const int4*)(eidx + E + e);    // dst
        unsigned v;
        v = (unsigned)(d4.x - lo); if (v < RANGE) atomicAdd(&acc[v], zs[s4.x]);
        v = (unsigned)(d4.y - lo); if (v < RANGE) atomicAdd(&acc[v], zs[s4.y]);
        v = (unsigned)(d4.z - lo); if (v < RANGE) atomicAdd(&acc[v], zs[s4.z]);
        v = (unsigned)(d4.w - lo); if (v < RANGE) atomicAdd(&acc[v], zs[s4.w]);
    }
    __syncthreads();

    float* outp = partf + (size_t)blockIdx.x * RANGE;
    for (int i = threadIdx.x; i < RANGE; i += SCAN_TPB) outp[i] = acc[i];
}

// ------- final: out = dinv * (sum partials + zs[self]) + (b_g.W_out + b_out) -------
__global__ __launch_bounds__(256) void k_redFinal(const float* __restrict__ partf,
                                                  const float* __restrict__ dinv,
                                                  const float* __restrict__ zs,
                                                  const float* __restrict__ b_g,
                                                  const float* __restrict__ W_out,
                                                  const float* __restrict__ b_out,
                                                  float* __restrict__ out, int N) {
    const int lane = threadIdx.x & 63;
    float c = b_g[lane] * W_out[lane];
#pragma unroll
    for (int off = 32; off > 0; off >>= 1)
        c += __shfl_xor(c, off, 64);
    c += b_out[0];

    int i = blockIdx.x * blockDim.x + threadIdx.x;
    if (i >= N) return;
    const int r = i >> RANGE_BITS, idx = i & (RANGE - 1);
    float a = zs[i];   // self-loop
#pragma unroll 4
    for (int m = 0; m < MCH; ++m)
        a += partf[((size_t)m * NB + r) * RANGE + idx];
    out[i] = fmaf(dinv[i], a, c);
}

// ---------------- launch ----------------

extern "C" void kernel_launch(void* const* d_in, const int* in_sizes, int n_in,
                              void* d_out, int out_size, void* d_ws, size_t ws_size,
                              hipStream_t stream) {
    const float* x     = (const float*)d_in[0];
    const int*   eidx  = (const int*)d_in[1];
    const float* W_in  = (const float*)d_in[2];
    const float* b_in  = (const float*)d_in[3];
    const float* W_g   = (const float*)d_in[4];
    const float* b_g   = (const float*)d_in[5];
    const float* W_out = (const float*)d_in[6];
    const float* b_out = (const float*)d_in[7];
    float* out = (float*)d_out;

    const int N = in_sizes[0] / IN_DIM;   // 100000
    const int E = in_sizes[1] / 2;        // 1600000

    // chunks: multiples of 4
    const int chunk  = (((E + MCH  - 1) / MCH ) + 3) & ~3;
    const int chunkA = (((E + MCH2 - 1) / MCH2) + 3) & ~3;

    // ws layout: region0 = max(partf 16.5MB, partA 16.8MB u32) | zpart[4*Npad] | dinv[N] | zs[N]
    const size_t partElems0 = (size_t)NB * MCH * RANGE;              // binC floats
    const size_t partElemsA = (size_t)NB2 * MCH2 * (RANGE2 / 2);     // binA u32 words
    const size_t partElems = partElems0 > partElemsA ? partElems0 : partElemsA;
    const int Npad = (N + 63) & ~63;
    unsigned* partA = (unsigned*)d_ws;    // consumed by redDeg before binC overwrites
    float*    partf = (float*)d_ws;
    float*    zpart = (float*)d_ws + partElems;
    float*    dinv  = zpart + 4 * (size_t)Npad;
    float*    zs    = dinv + N;

    const int nG = (N + DNODES - 1) / DNODES;   // 1563 dense blocks
    k_binA<<<NB2 * MCH2, SCAN_TPB, 0, stream>>>(eidx + E, partA, E, chunkA);
    k_dense<<<nG, 256, 0, stream>>>(x, W_in, b_in, W_g, W_out, zpart, N, Npad);
    k_redDeg<<<(N + 255) / 256, 256, 0, stream>>>(partA, zpart, dinv, zs, N, Npad);
    k_binC<<<NB * MCH, SCAN_TPB, 0, stream>>>(eidx, zs, partf, E, chunk);
    k_redFinal<<<(N + 255) / 256, 256, 0, stream>>>(partf, dinv, zs, b_g, W_out, b_out, out, N);
}